// Round 2
// baseline (4709.461 us; speedup 1.0000x reference)
//
#include <hip/hip_runtime.h>

#define NN 100000
#define NE 3200000
#define NG 256
#define H 32

#define NB_D 391              // dst buckets: (99999>>8)+1
#define NST 7                 // src tiles:   (99999>>14)+1
#define NBK (NST * NB_D)      // 2737 total buckets

// Monotone bijection float -> u32 (order-preserving), so u32 max == float max.
__device__ __forceinline__ unsigned encf(float f) {
    unsigned u = __float_as_uint(f);
    return (u & 0x80000000u) ? ~u : (u | 0x80000000u);
}
__device__ __forceinline__ float decf(unsigned u) {
    return __uint_as_float((u & 0x80000000u) ? (u & 0x7fffffffu) : ~u);
}
__device__ __forceinline__ int bucket_of(int s, int d) {
    return (s >> 14) * NB_D + (d >> 8);
}

// Init agg (enc(0) folds neginf->0 fill AND relu), g, and bucket histogram.
__global__ __launch_bounds__(256) void k_init(unsigned* __restrict__ agg,
                                              unsigned* __restrict__ g,
                                              unsigned* __restrict__ hist) {
    int i = blockIdx.x * 256 + threadIdx.x;   // grid covers exactly NN*H
    agg[i] = 0x80000000u;
    if (i < NG * H) g[i] = 0x80000000u;
    if (i < NBK) hist[i] = 0u;
}

__global__ __launch_bounds__(256) void k_reset(unsigned* __restrict__ agg) {
    int i = blockIdx.x * 256 + threadIdx.x;
    agg[i] = 0x80000000u;
}

// Bucket histogram: per-block LDS hist, one global add per bucket per block.
__global__ __launch_bounds__(256) void k_hist(const int* __restrict__ src,
                                              const int* __restrict__ dst,
                                              unsigned* __restrict__ hist) {
    __shared__ unsigned lh[NBK];
    int tid = threadIdx.x;
    for (int i = tid; i < NBK; i += 256) lh[i] = 0u;
    __syncthreads();
    for (int e = blockIdx.x * 256 + tid; e < NE; e += gridDim.x * 256)
        atomicAdd(&lh[bucket_of(src[e], dst[e])], 1u);
    __syncthreads();
    for (int i = tid; i < NBK; i += 256) {
        unsigned c = lh[i];
        if (c) atomicAdd(&hist[i], c);
    }
}

// Exclusive scan of 2737 counters by one wave (43 buckets/lane + wave scan).
__global__ __launch_bounds__(64) void k_scan(const unsigned* __restrict__ hist,
                                             unsigned* __restrict__ offsets,
                                             unsigned* __restrict__ cursors) {
    int lane = threadIdx.x;
    const int CH = 43;  // 43*64 >= NBK
    int base = lane * CH;
    unsigned s = 0;
    for (int j = 0; j < CH; j++) {
        int idx = base + j;
        if (idx < NBK) s += hist[idx];
    }
    unsigned run = s;
    for (int off = 1; off < 64; off <<= 1) {
        unsigned v = __shfl_up(run, off);
        if (lane >= off) run += v;
    }
    unsigned acc = run - s;  // exclusive prefix of this lane's chunk
    for (int j = 0; j < CH; j++) {
        int idx = base + j;
        if (idx < NBK) {
            offsets[idx] = acc;
            cursors[idx] = acc;
            acc += hist[idx];
        }
    }
    if (lane == 63) offsets[NBK] = acc;  // == NE
}

// Scatter edges into bucket-sorted order, packed: (src&16383)<<8 | (dst&255).
// Order within a bucket is nondeterministic but max-reduction is order-free.
__global__ __launch_bounds__(256) void k_scatter(const int* __restrict__ src,
                                                 const int* __restrict__ dst,
                                                 unsigned* __restrict__ cursors,
                                                 unsigned* __restrict__ sorted) {
    int e = blockIdx.x * 256 + threadIdx.x;  // grid covers exactly NE
    int s = src[e], d = dst[e];
    int b = bucket_of(s, d);
    unsigned slot = atomicAdd(&cursors[b], 1u);
    sorted[slot] = ((unsigned)(s & 16383) << 8) | (unsigned)(d & 255);
}

// Layer-1 edge kernel. One block per bucket; 256-dst bucket aggregated in LDS.
// t_k = relu( sum_i ps_i*W1a[i][k] + (ps_i-pd_i)*W1a[3+i][k] + b1a[k] )
// msg = t @ W1b + b1b ; LDS atomicMax (enc domain); flush with test-atomic.
__global__ __launch_bounds__(256) void k_edge1(const unsigned* __restrict__ sorted,
                                               const unsigned* __restrict__ offsets,
                                               const float* __restrict__ pos,
                                               const float* __restrict__ W1a,
                                               const float* __restrict__ b1a,
                                               const float* __restrict__ W1b,
                                               const float* __restrict__ b1b,
                                               unsigned* __restrict__ agg) {
    __shared__ unsigned lagg[256 * 33];  // pad 33: ~2-way bank aliasing (free)
    int tid = threadIdx.x;
    for (int i = tid; i < 256 * 33; i += 256) lagg[i] = 0x80000000u;
    __syncthreads();
    int b = blockIdx.x;
    int st = b / NB_D, dtb = b - st * NB_D;
    int lo = (int)offsets[b], hi = (int)offsets[b + 1];
    int dbase = dtb << 8;
    for (int i = lo + tid; i < hi; i += 256) {
        unsigned p = sorted[i];
        int s = (st << 14) | (int)(p >> 8);
        int dl = (int)(p & 255u);
        int d = dbase + dl;
        float ps0 = pos[3 * s], ps1 = pos[3 * s + 1], ps2 = pos[3 * s + 2];
        float pd0 = pos[3 * d], pd1 = pos[3 * d + 1], pd2 = pos[3 * d + 2];
        float e0 = ps0 - pd0, e1 = ps1 - pd1, e2 = ps2 - pd2;
        float t[H];
#pragma unroll
        for (int k = 0; k < H; k++) {
            float v = b1a[k];
            v = fmaf(ps0, W1a[k], v);
            v = fmaf(ps1, W1a[32 + k], v);
            v = fmaf(ps2, W1a[64 + k], v);
            v = fmaf(e0, W1a[96 + k], v);
            v = fmaf(e1, W1a[128 + k], v);
            v = fmaf(e2, W1a[160 + k], v);
            t[k] = fmaxf(v, 0.f);
        }
        float m[H];
#pragma unroll
        for (int k = 0; k < H; k++) m[k] = b1b[k];
#pragma unroll
        for (int j = 0; j < H; j++) {
            float tj = t[j];
#pragma unroll
            for (int k = 0; k < H; k++) m[k] = fmaf(tj, W1b[j * H + k], m[k]);
        }
#pragma unroll
        for (int k = 0; k < H; k++) {
            unsigned v = encf(m[k]);
            if (v > 0x80000000u) atomicMax(&lagg[dl * 33 + k], v);  // skip msg<=0
        }
    }
    __syncthreads();
    int node = dbase + tid;
    if (node < NN) {
        unsigned* ag = agg + (size_t)node * H;
#pragma unroll
        for (int r = 0; r < 8; r++) {
            uint4 c = ((const uint4*)ag)[r];
            unsigned l0 = lagg[tid * 33 + 4 * r + 0];
            unsigned l1 = lagg[tid * 33 + 4 * r + 1];
            unsigned l2 = lagg[tid * 33 + 4 * r + 2];
            unsigned l3 = lagg[tid * 33 + 4 * r + 3];
            if (l0 > c.x) atomicMax(ag + 4 * r + 0, l0);
            if (l1 > c.y) atomicMax(ag + 4 * r + 1, l1);
            if (l2 > c.z) atomicMax(ag + 4 * r + 2, l2);
            if (l3 > c.w) atomicMax(ag + 4 * r + 3, l3);
        }
    }
}

// Layer-2 per-node precompute: E2[n] = b2a + h[n]@W2a[0:32] + pos[n]@W2a[32:35]
__global__ __launch_bounds__(256) void k_pre2(const float* __restrict__ pos,
                                              const unsigned* __restrict__ agg,
                                              const float* __restrict__ W2a,
                                              const float* __restrict__ b2a,
                                              float* __restrict__ E2) {
    int n = blockIdx.x * 256 + threadIdx.x;
    if (n >= NN) return;
    float h[H];
    const uint4* A4 = (const uint4*)(agg + (size_t)n * H);
#pragma unroll
    for (int r = 0; r < 8; r++) {
        uint4 u = A4[r];
        h[4 * r + 0] = decf(u.x);
        h[4 * r + 1] = decf(u.y);
        h[4 * r + 2] = decf(u.z);
        h[4 * r + 3] = decf(u.w);
    }
    float p0 = pos[3 * n], p1 = pos[3 * n + 1], p2 = pos[3 * n + 2];
    float ev[H];
#pragma unroll
    for (int k = 0; k < H; k++) {
        float v = b2a[k];
        v = fmaf(p0, W2a[32 * H + k], v);
        v = fmaf(p1, W2a[33 * H + k], v);
        v = fmaf(p2, W2a[34 * H + k], v);
        ev[k] = v;
    }
#pragma unroll
    for (int j = 0; j < H; j++) {
        float hj = h[j];
#pragma unroll
        for (int k = 0; k < H; k++) ev[k] = fmaf(hj, W2a[j * H + k], ev[k]);
    }
    float4* E4 = (float4*)(E2 + (size_t)n * H);
#pragma unroll
    for (int r = 0; r < 8; r++)
        E4[r] = make_float4(ev[4 * r], ev[4 * r + 1], ev[4 * r + 2], ev[4 * r + 3]);
}

// Layer-2 edge kernel: t = relu(E2[src] - pos[dst]@W2a[32:35]); msg = t@W2b+b2b.
__global__ __launch_bounds__(256) void k_edge2(const unsigned* __restrict__ sorted,
                                               const unsigned* __restrict__ offsets,
                                               const float* __restrict__ pos,
                                               const float* __restrict__ E2,
                                               const float* __restrict__ W2a,
                                               const float* __restrict__ W2b,
                                               const float* __restrict__ b2b,
                                               unsigned* __restrict__ agg) {
    __shared__ unsigned lagg[256 * 33];
    int tid = threadIdx.x;
    for (int i = tid; i < 256 * 33; i += 256) lagg[i] = 0x80000000u;
    __syncthreads();
    int b = blockIdx.x;
    int st = b / NB_D, dtb = b - st * NB_D;
    int lo = (int)offsets[b], hi = (int)offsets[b + 1];
    int dbase = dtb << 8;
    for (int i = lo + tid; i < hi; i += 256) {
        unsigned p = sorted[i];
        int s = (st << 14) | (int)(p >> 8);
        int dl = (int)(p & 255u);
        int d = dbase + dl;
        float pd0 = pos[3 * d], pd1 = pos[3 * d + 1], pd2 = pos[3 * d + 2];
        const float4* er = (const float4*)(E2 + (size_t)s * H);
        float t[H];
#pragma unroll
        for (int r = 0; r < 8; r++) {
            float4 e4 = er[r];
#pragma unroll
            for (int q = 0; q < 4; q++) {
                int k = 4 * r + q;
                float ek = (q == 0) ? e4.x : (q == 1) ? e4.y : (q == 2) ? e4.z : e4.w;
                float v = fmaf(-pd0, W2a[32 * H + k],
                          fmaf(-pd1, W2a[33 * H + k],
                          fmaf(-pd2, W2a[34 * H + k], ek)));
                t[k] = fmaxf(v, 0.f);
            }
        }
        float m[H];
#pragma unroll
        for (int k = 0; k < H; k++) m[k] = b2b[k];
#pragma unroll
        for (int j = 0; j < H; j++) {
            float tj = t[j];
#pragma unroll
            for (int k = 0; k < H; k++) m[k] = fmaf(tj, W2b[j * H + k], m[k]);
        }
#pragma unroll
        for (int k = 0; k < H; k++) {
            unsigned v = encf(m[k]);
            if (v > 0x80000000u) atomicMax(&lagg[dl * 33 + k], v);
        }
    }
    __syncthreads();
    int node = dbase + tid;
    if (node < NN) {
        unsigned* ag = agg + (size_t)node * H;
#pragma unroll
        for (int r = 0; r < 8; r++) {
            uint4 c = ((const uint4*)ag)[r];
            unsigned l0 = lagg[tid * 33 + 4 * r + 0];
            unsigned l1 = lagg[tid * 33 + 4 * r + 1];
            unsigned l2 = lagg[tid * 33 + 4 * r + 2];
            unsigned l3 = lagg[tid * 33 + 4 * r + 3];
            if (l0 > c.x) atomicMax(ag + 4 * r + 0, l0);
            if (l1 > c.y) atomicMax(ag + 4 * r + 1, l1);
            if (l2 > c.z) atomicMax(ag + 4 * r + 2, l2);
            if (l3 > c.w) atomicMax(ag + 4 * r + 3, l3);
        }
    }
}

// Graph max-pool (encoded domain; max commutes with monotone encoding).
__global__ __launch_bounds__(256) void k_pool(const unsigned* __restrict__ agg,
                                              const int* __restrict__ batch,
                                              unsigned* __restrict__ g) {
    int n = blockIdx.x * 256 + threadIdx.x;
    if (n >= NN) return;
    int bidx = batch[n];
    unsigned* gb = g + (size_t)bidx * H;
    const uint4* A4 = (const uint4*)(agg + (size_t)n * H);
#pragma unroll
    for (int r = 0; r < 8; r++) {
        uint4 v = A4[r];
        uint4 c = ((const uint4*)gb)[r];
        if (v.x > c.x) atomicMax(gb + 4 * r + 0, v.x);
        if (v.y > c.y) atomicMax(gb + 4 * r + 1, v.y);
        if (v.z > c.z) atomicMax(gb + 4 * r + 2, v.z);
        if (v.w > c.w) atomicMax(gb + 4 * r + 3, v.w);
    }
}

__global__ __launch_bounds__(256) void k_out(const unsigned* __restrict__ g,
                                             const float* __restrict__ Wout,
                                             const float* __restrict__ bout,
                                             float* __restrict__ out) {
    int bidx = threadIdx.x;  // one block of 256
    float acc = bout[0];
#pragma unroll
    for (int k = 0; k < H; k++) acc = fmaf(decf(g[bidx * H + k]), Wout[k], acc);
    out[bidx] = acc;
}

extern "C" void kernel_launch(void* const* d_in, const int* in_sizes, int n_in,
                              void* d_out, int out_size, void* d_ws, size_t ws_size,
                              hipStream_t stream) {
    const float* pos  = (const float*)d_in[0];
    const int* src    = (const int*)d_in[1];
    const int* dst    = src + NE;
    const int* batch  = (const int*)d_in[2];
    const float* W1a  = (const float*)d_in[3];
    const float* b1a  = (const float*)d_in[4];
    const float* W1b  = (const float*)d_in[5];
    const float* b1b  = (const float*)d_in[6];
    const float* W2a  = (const float*)d_in[7];
    const float* b2a  = (const float*)d_in[8];
    const float* W2b  = (const float*)d_in[9];
    const float* b2b  = (const float*)d_in[10];
    const float* Wout = (const float*)d_in[11];
    const float* bout = (const float*)d_in[12];
    float* out = (float*)d_out;

    const size_t SZ = (size_t)NN * H;  // 3.2M elems per node-feature buffer
    unsigned* agg     = (unsigned*)d_ws;              // 12.8 MB (both layers)
    float* E2         = (float*)d_ws + SZ;            // 12.8 MB
    unsigned* sorted  = (unsigned*)d_ws + 2 * SZ;     // 12.8 MB (both layers)
    unsigned* g       = (unsigned*)d_ws + 3 * SZ;     // 32 KB
    unsigned* hist    = g + (size_t)NG * H;           // NBK
    unsigned* offsets = hist + NBK;                   // NBK+1
    unsigned* cursors = offsets + NBK + 1;            // NBK

    const int AGG_BLOCKS  = (NN * H) / 256;  // 12500, exact
    const int EDGE_BLOCKS = NE / 256;        // 12500, exact
    const int NODE_BLOCKS = (NN + 255) / 256;

    k_init<<<AGG_BLOCKS, 256, 0, stream>>>(agg, g, hist);
    k_hist<<<512, 256, 0, stream>>>(src, dst, hist);
    k_scan<<<1, 64, 0, stream>>>(hist, offsets, cursors);
    k_scatter<<<EDGE_BLOCKS, 256, 0, stream>>>(src, dst, cursors, sorted);
    k_edge1<<<NBK, 256, 0, stream>>>(sorted, offsets, pos, W1a, b1a, W1b, b1b, agg);
    k_pre2<<<NODE_BLOCKS, 256, 0, stream>>>(pos, agg, W2a, b2a, E2);
    k_reset<<<AGG_BLOCKS, 256, 0, stream>>>(agg);
    k_edge2<<<NBK, 256, 0, stream>>>(sorted, offsets, pos, E2, W2a, W2b, b2b, agg);
    k_pool<<<NODE_BLOCKS, 256, 0, stream>>>(agg, batch, g);
    k_out<<<1, 256, 0, stream>>>(g, Wout, bout, out);
}

// Round 3
// 1966.944 us; speedup vs baseline: 2.3943x; 2.3943x over previous
//
#include <hip/hip_runtime.h>

#define NN 100000
#define NE 3200000
#define NG 256
#define H 32
#define CE 8                     // edges per thread chunk
#define NCH (NE / CE)            // 400000 chunks
#define SB ((NN + 255) / 256)    // 391 scan blocks

// Monotone bijection float -> u32 (order-preserving), so u32 max == float max.
__device__ __forceinline__ unsigned encf(float f) {
    unsigned u = __float_as_uint(f);
    return (u & 0x80000000u) ? ~u : (u | 0x80000000u);
}
__device__ __forceinline__ float decf(unsigned u) {
    return __uint_as_float((u & 0x80000000u) ? (u & 0x7fffffffu) : ~u);
}

// Flush a register-held run max to global agg (enc domain, test-before-atomic).
// agg starts at enc(0): values <=0 never pass the test (folds relu + neginf fill).
__device__ __forceinline__ void flush_row(unsigned* __restrict__ agg, int node,
                                          const float* m) {
    unsigned* ag = agg + (size_t)node * H;
#pragma unroll
    for (int r = 0; r < 8; r++) {
        uint4 c = ((const uint4*)ag)[r];
        unsigned v0 = encf(m[4 * r + 0]);
        unsigned v1 = encf(m[4 * r + 1]);
        unsigned v2 = encf(m[4 * r + 2]);
        unsigned v3 = encf(m[4 * r + 3]);
        if (v0 > c.x) atomicMax(ag + 4 * r + 0, v0);
        if (v1 > c.y) atomicMax(ag + 4 * r + 1, v1);
        if (v2 > c.z) atomicMax(ag + 4 * r + 2, v2);
        if (v3 > c.w) atomicMax(ag + 4 * r + 3, v3);
    }
}

// init agg=enc(0), g=enc(0), hist=0, chunk_node=~0. Grid covers NN*H = 3.2M.
__global__ __launch_bounds__(256) void k_init(unsigned* __restrict__ agg,
                                              unsigned* __restrict__ g,
                                              unsigned* __restrict__ hist,
                                              unsigned* __restrict__ chunk_node) {
    int i = blockIdx.x * 256 + threadIdx.x;
    agg[i] = 0x80000000u;
    if (i < NG * H) g[i] = 0x80000000u;
    if (i < NN) hist[i] = 0u;
    if (i < NCH) chunk_node[i] = 0xFFFFFFFFu;
}

__global__ __launch_bounds__(256) void k_hist(const int* __restrict__ dst,
                                              unsigned* __restrict__ hist) {
    int e = blockIdx.x * 256 + threadIdx.x;   // grid covers exactly NE
    atomicAdd(&hist[dst[e]], 1u);
}

// Block-level exclusive scan (Hillis-Steele in LDS), 256 elems/block.
__global__ __launch_bounds__(256) void k_scan1(const unsigned* __restrict__ hist,
                                               unsigned* __restrict__ pre,
                                               unsigned* __restrict__ bsum) {
    __shared__ unsigned sd[256];
    int tid = threadIdx.x;
    int i = blockIdx.x * 256 + tid;
    unsigned v = (i < NN) ? hist[i] : 0u;
    sd[tid] = v;
    __syncthreads();
    for (int off = 1; off < 256; off <<= 1) {
        unsigned t = (tid >= off) ? sd[tid - off] : 0u;
        __syncthreads();
        sd[tid] += t;
        __syncthreads();
    }
    if (i < NN) pre[i] = sd[tid] - v;
    if (tid == 255) bsum[blockIdx.x] = sd[255];
}

__global__ __launch_bounds__(512) void k_scan2(const unsigned* __restrict__ bsum,
                                               unsigned* __restrict__ bpre) {
    __shared__ unsigned sd[512];
    int t = threadIdx.x;
    unsigned v = (t < SB) ? bsum[t] : 0u;
    sd[t] = v;
    __syncthreads();
    for (int off = 1; off < 512; off <<= 1) {
        unsigned x = (t >= off) ? sd[t - off] : 0u;
        __syncthreads();
        sd[t] += x;
        __syncthreads();
    }
    if (t < SB) bpre[t] = sd[t] - v;
}

// cursors[i] = global exclusive prefix (scatter cursor); ends[i] = prefix+count.
__global__ __launch_bounds__(256) void k_scan3(const unsigned* __restrict__ pre,
                                               const unsigned* __restrict__ bpre,
                                               const unsigned* __restrict__ hist,
                                               unsigned* __restrict__ cursors,
                                               unsigned* __restrict__ ends) {
    int i = blockIdx.x * 256 + threadIdx.x;
    if (i < NN) {
        unsigned o = pre[i] + bpre[blockIdx.x];
        cursors[i] = o;
        ends[i] = o + hist[i];
    }
}

// Scatter src ids into dst-sorted order; record first (=min) dst of each 8-chunk.
__global__ __launch_bounds__(256) void k_scatter(const int* __restrict__ src,
                                                 const int* __restrict__ dst,
                                                 unsigned* __restrict__ cursors,
                                                 unsigned* __restrict__ srcS,
                                                 unsigned* __restrict__ chunk_node) {
    int e = blockIdx.x * 256 + threadIdx.x;   // grid covers exactly NE
    int d = dst[e];
    unsigned slot = atomicAdd(&cursors[d], 1u);
    srcS[slot] = (unsigned)src[e];
    atomicMin(&chunk_node[slot >> 3], (unsigned)d);
}

// Layer-1 edge kernel: 8 dst-sorted edges/thread, register run-max, flush at
// run boundaries. t = relu(b1a + ps@Wh + (ps-pd)@Wt); msg = t@W1b + b1b.
__global__ __launch_bounds__(256) void k_edge1(const unsigned* __restrict__ srcS,
                                               const unsigned* __restrict__ ends,
                                               const unsigned* __restrict__ chunk_node,
                                               const float* __restrict__ pos,
                                               const float* __restrict__ W1a,
                                               const float* __restrict__ b1a,
                                               const float* __restrict__ W1b,
                                               const float* __restrict__ b1b,
                                               unsigned* __restrict__ agg) {
    int gid = blockIdx.x * 256 + threadIdx.x;
    if (gid >= NCH) return;
    unsigned base = (unsigned)gid * CE;
    int cur = (int)chunk_node[gid];
    unsigned end_cur = ends[cur];
    float pd0 = pos[3 * cur], pd1 = pos[3 * cur + 1], pd2 = pos[3 * cur + 2];
    float macc[H];
#pragma unroll
    for (int k = 0; k < H; k++) macc[k] = 0.f;
    for (int c = 0; c < CE; c++) {
        unsigned e = base + c;
        if (e >= end_cur) {
            flush_row(agg, cur, macc);
            do { cur++; end_cur = ends[cur]; } while (e >= end_cur);
            pd0 = pos[3 * cur]; pd1 = pos[3 * cur + 1]; pd2 = pos[3 * cur + 2];
#pragma unroll
            for (int k = 0; k < H; k++) macc[k] = 0.f;
        }
        int s = (int)srcS[e];
        float ps0 = pos[3 * s], ps1 = pos[3 * s + 1], ps2 = pos[3 * s + 2];
        float e0 = ps0 - pd0, e1 = ps1 - pd1, e2 = ps2 - pd2;
        float t[H];
#pragma unroll
        for (int k = 0; k < H; k++) {
            float v = b1a[k];
            v = fmaf(ps0, W1a[k], v);
            v = fmaf(ps1, W1a[32 + k], v);
            v = fmaf(ps2, W1a[64 + k], v);
            v = fmaf(e0, W1a[96 + k], v);
            v = fmaf(e1, W1a[128 + k], v);
            v = fmaf(e2, W1a[160 + k], v);
            t[k] = fmaxf(v, 0.f);
        }
        float m[H];
#pragma unroll
        for (int k = 0; k < H; k++) m[k] = b1b[k];
#pragma unroll
        for (int j = 0; j < H; j++) {
            float tj = t[j];
#pragma unroll
            for (int k = 0; k < H; k++) m[k] = fmaf(tj, W1b[j * H + k], m[k]);
        }
#pragma unroll
        for (int k = 0; k < H; k++) macc[k] = fmaxf(macc[k], m[k]);
    }
    flush_row(agg, cur, macc);
}

// Layer-2 node precompute: E2[n] = b2a + h[n]@W2a[0:32] + pos[n]@W2a[32:35];
// also resets agg row for reuse by layer 2 (each thread owns its row).
__global__ __launch_bounds__(256) void k_pre2(const float* __restrict__ pos,
                                              unsigned* __restrict__ agg,
                                              const float* __restrict__ W2a,
                                              const float* __restrict__ b2a,
                                              float* __restrict__ E2) {
    int n = blockIdx.x * 256 + threadIdx.x;
    if (n >= NN) return;
    float h[H];
    uint4* A4 = (uint4*)(agg + (size_t)n * H);
#pragma unroll
    for (int r = 0; r < 8; r++) {
        uint4 u = A4[r];
        h[4 * r + 0] = decf(u.x);
        h[4 * r + 1] = decf(u.y);
        h[4 * r + 2] = decf(u.z);
        h[4 * r + 3] = decf(u.w);
        A4[r] = make_uint4(0x80000000u, 0x80000000u, 0x80000000u, 0x80000000u);
    }
    float p0 = pos[3 * n], p1 = pos[3 * n + 1], p2 = pos[3 * n + 2];
    float ev[H];
#pragma unroll
    for (int k = 0; k < H; k++) {
        float v = b2a[k];
        v = fmaf(p0, W2a[32 * H + k], v);
        v = fmaf(p1, W2a[33 * H + k], v);
        v = fmaf(p2, W2a[34 * H + k], v);
        ev[k] = v;
    }
#pragma unroll
    for (int j = 0; j < H; j++) {
        float hj = h[j];
#pragma unroll
        for (int k = 0; k < H; k++) ev[k] = fmaf(hj, W2a[j * H + k], ev[k]);
    }
    float4* E4 = (float4*)(E2 + (size_t)n * H);
#pragma unroll
    for (int r = 0; r < 8; r++)
        E4[r] = make_float4(ev[4 * r], ev[4 * r + 1], ev[4 * r + 2], ev[4 * r + 3]);
}

// Layer-2 edge kernel: t = relu(E2[src] - fd), fd = pos[dst]@W2a[32:35]
// recomputed only at run boundaries; msg = t@W2b + b2b (4 groups of 8 to cap VGPR).
__global__ __launch_bounds__(256) void k_edge2(const unsigned* __restrict__ srcS,
                                               const unsigned* __restrict__ ends,
                                               const unsigned* __restrict__ chunk_node,
                                               const float* __restrict__ pos,
                                               const float* __restrict__ E2,
                                               const float* __restrict__ W2a,
                                               const float* __restrict__ W2b,
                                               const float* __restrict__ b2b,
                                               unsigned* __restrict__ agg) {
    int gid = blockIdx.x * 256 + threadIdx.x;
    if (gid >= NCH) return;
    unsigned base = (unsigned)gid * CE;
    int cur = (int)chunk_node[gid];
    unsigned end_cur = ends[cur];
    float fd[H];
    {
        float pd0 = pos[3 * cur], pd1 = pos[3 * cur + 1], pd2 = pos[3 * cur + 2];
#pragma unroll
        for (int k = 0; k < H; k++)
            fd[k] = fmaf(pd0, W2a[32 * H + k],
                    fmaf(pd1, W2a[33 * H + k], pd2 * W2a[34 * H + k]));
    }
    float macc[H];
#pragma unroll
    for (int k = 0; k < H; k++) macc[k] = 0.f;
    for (int c = 0; c < CE; c++) {
        unsigned e = base + c;
        if (e >= end_cur) {
            flush_row(agg, cur, macc);
            do { cur++; end_cur = ends[cur]; } while (e >= end_cur);
            float pd0 = pos[3 * cur], pd1 = pos[3 * cur + 1], pd2 = pos[3 * cur + 2];
#pragma unroll
            for (int k = 0; k < H; k++)
                fd[k] = fmaf(pd0, W2a[32 * H + k],
                        fmaf(pd1, W2a[33 * H + k], pd2 * W2a[34 * H + k]));
#pragma unroll
            for (int k = 0; k < H; k++) macc[k] = 0.f;
        }
        int s = (int)srcS[e];
        const float4* er = (const float4*)(E2 + (size_t)s * H);
        float t[H];
#pragma unroll
        for (int r = 0; r < 8; r++) {
            float4 v = er[r];
            t[4 * r + 0] = fmaxf(v.x - fd[4 * r + 0], 0.f);
            t[4 * r + 1] = fmaxf(v.y - fd[4 * r + 1], 0.f);
            t[4 * r + 2] = fmaxf(v.z - fd[4 * r + 2], 0.f);
            t[4 * r + 3] = fmaxf(v.w - fd[4 * r + 3], 0.f);
        }
#pragma unroll
        for (int grp = 0; grp < 4; grp++) {
            float m[8];
#pragma unroll
            for (int k = 0; k < 8; k++) m[k] = b2b[grp * 8 + k];
#pragma unroll
            for (int j = 0; j < H; j++) {
                float tj = t[j];
#pragma unroll
                for (int k = 0; k < 8; k++)
                    m[k] = fmaf(tj, W2b[j * H + grp * 8 + k], m[k]);
            }
#pragma unroll
            for (int k = 0; k < 8; k++)
                macc[grp * 8 + k] = fmaxf(macc[grp * 8 + k], m[k]);
        }
    }
    flush_row(agg, cur, macc);
}

// Graph max-pool (encoded domain; max commutes with monotone encoding).
__global__ __launch_bounds__(256) void k_pool(const unsigned* __restrict__ agg,
                                              const int* __restrict__ batch,
                                              unsigned* __restrict__ g) {
    int n = blockIdx.x * 256 + threadIdx.x;
    if (n >= NN) return;
    int bidx = batch[n];
    unsigned* gb = g + (size_t)bidx * H;
    const uint4* A4 = (const uint4*)(agg + (size_t)n * H);
#pragma unroll
    for (int r = 0; r < 8; r++) {
        uint4 v = A4[r];
        uint4 c = ((const uint4*)gb)[r];
        if (v.x > c.x) atomicMax(gb + 4 * r + 0, v.x);
        if (v.y > c.y) atomicMax(gb + 4 * r + 1, v.y);
        if (v.z > c.z) atomicMax(gb + 4 * r + 2, v.z);
        if (v.w > c.w) atomicMax(gb + 4 * r + 3, v.w);
    }
}

__global__ __launch_bounds__(256) void k_out(const unsigned* __restrict__ g,
                                             const float* __restrict__ Wout,
                                             const float* __restrict__ bout,
                                             float* __restrict__ out) {
    int bidx = threadIdx.x;  // one block of 256
    float acc = bout[0];
#pragma unroll
    for (int k = 0; k < H; k++) acc = fmaf(decf(g[bidx * H + k]), Wout[k], acc);
    out[bidx] = acc;
}

extern "C" void kernel_launch(void* const* d_in, const int* in_sizes, int n_in,
                              void* d_out, int out_size, void* d_ws, size_t ws_size,
                              hipStream_t stream) {
    const float* pos  = (const float*)d_in[0];
    const int* src    = (const int*)d_in[1];
    const int* dst    = src + NE;
    const int* batch  = (const int*)d_in[2];
    const float* W1a  = (const float*)d_in[3];
    const float* b1a  = (const float*)d_in[4];
    const float* W1b  = (const float*)d_in[5];
    const float* b1b  = (const float*)d_in[6];
    const float* W2a  = (const float*)d_in[7];
    const float* b2a  = (const float*)d_in[8];
    const float* W2b  = (const float*)d_in[9];
    const float* b2b  = (const float*)d_in[10];
    const float* Wout = (const float*)d_in[11];
    const float* bout = (const float*)d_in[12];
    float* out = (float*)d_out;

    const size_t SZ = (size_t)NN * H;  // 3.2M words
    unsigned* agg        = (unsigned*)d_ws;          // 12.8 MB
    float*    E2         = (float*)d_ws + SZ;        // 12.8 MB (aliased pre-edge1)
    unsigned* srcS       = (unsigned*)d_ws + 2 * SZ; // 12.8 MB (dst-sorted src ids)
    unsigned* g          = (unsigned*)d_ws + 3 * SZ; // 32 KB
    unsigned* ends       = g + NG * H;               // 400 KB (CSR run ends)
    unsigned* chunk_node = ends + NN;                // 1.6 MB (first dst per chunk)
    unsigned* bsum       = chunk_node + NCH;         // scan partials
    unsigned* bpre       = bsum + SB + 1;
    // Sort-phase temporaries aliased into E2's space (dead before k_pre2 writes):
    unsigned* hist    = (unsigned*)E2;
    unsigned* pre     = hist + NN;
    unsigned* cursors = pre + NN;

    const int EDGE_BLOCKS  = NE / 256;          // 12500
    const int INIT_BLOCKS  = (NN * H) / 256;    // 12500 (covers all init targets)
    const int NODE_BLOCKS  = SB;                // 391
    const int CHUNK_BLOCKS = (NCH + 255) / 256; // 1563

    k_init<<<INIT_BLOCKS, 256, 0, stream>>>(agg, g, hist, chunk_node);
    k_hist<<<EDGE_BLOCKS, 256, 0, stream>>>(dst, hist);
    k_scan1<<<NODE_BLOCKS, 256, 0, stream>>>(hist, pre, bsum);
    k_scan2<<<1, 512, 0, stream>>>(bsum, bpre);
    k_scan3<<<NODE_BLOCKS, 256, 0, stream>>>(pre, bpre, hist, cursors, ends);
    k_scatter<<<EDGE_BLOCKS, 256, 0, stream>>>(src, dst, cursors, srcS, chunk_node);
    k_edge1<<<CHUNK_BLOCKS, 256, 0, stream>>>(srcS, ends, chunk_node, pos,
                                              W1a, b1a, W1b, b1b, agg);
    k_pre2<<<NODE_BLOCKS, 256, 0, stream>>>(pos, agg, W2a, b2a, E2);
    k_edge2<<<CHUNK_BLOCKS, 256, 0, stream>>>(srcS, ends, chunk_node, pos, E2,
                                              W2a, W2b, b2b, agg);
    k_pool<<<NODE_BLOCKS, 256, 0, stream>>>(agg, batch, g);
    k_out<<<1, 256, 0, stream>>>(g, Wout, bout, out);
}